// Round 2
// baseline (1596.036 us; speedup 1.0000x reference)
//
#include <hip/hip_runtime.h>

#define DIN 128
#define DH 64
#define DOUT 32
#define BN_EPS 1e-5f

#define BK 128          // nodes per bucket
#define BKSH 7          // log2(BK)
#define CAP 2560        // max edges per bucket (mean ~2046, +11 sigma)

// ---------------- bucket binning: recs[b*CAP + k] = (src<<7) | dst_local ----------------

__global__ __launch_bounds__(256) void binscatter_k(const int* __restrict__ src, const int* __restrict__ dst,
                                                    int* __restrict__ cnt, unsigned* __restrict__ recs, int E) {
    int i = blockIdx.x * 256 + threadIdx.x;
    if (i < E) {
        int s = src[i], d = dst[i];
        int b = d >> BKSH, dl = d & (BK - 1);
        int r = atomicAdd(&cnt[b], 1);
        if (r < CAP) recs[b * CAP + r] = ((unsigned)s << BKSH) | (unsigned)dl;
    }
}

// ---------------- per-bucket degree -> dis = rsqrt(deg+1) ----------------

__global__ __launch_bounds__(256) void deg_k(const unsigned* __restrict__ recs, const int* __restrict__ cnt,
                                             float* __restrict__ dis, int n) {
    __shared__ int deg[BK];
    int b = blockIdx.x;
    if (threadIdx.x < BK) deg[threadIdx.x] = 0;
    __syncthreads();
    int ne = min(cnt[b], CAP);
    const unsigned* base = recs + (size_t)b * CAP;
    for (int e = threadIdx.x; e < ne; e += 256)
        atomicAdd(&deg[base[e] & (BK - 1)], 1);
    __syncthreads();
    if (threadIdx.x < BK) {
        int g = b * BK + threadIdx.x;
        if (g < n) dis[g] = rsqrtf((float)(deg[threadIdx.x] + 1));  // +1 self-loop
    }
}

// ---------------- GEMM1: h1 = x @ W1  (N x 128 @ 128 x 64) ----------------

__global__ __launch_bounds__(256) void gemm1_k(const float* __restrict__ x, const float* __restrict__ W1,
                                               float* __restrict__ h1, int n) {
    __shared__ __attribute__((aligned(16))) float xs[64][132];
    __shared__ __attribute__((aligned(16))) float ws[128][64];
    int r0b = blockIdx.x * 64;

    const float4* w4 = (const float4*)W1;
    float4* ws4 = (float4*)&ws[0][0];
    for (int i = threadIdx.x; i < 2048; i += 256) ws4[i] = w4[i];
    for (int i = threadIdx.x; i < 2048; i += 256) {
        int lin = i * 4;
        int r = lin >> 7, k = lin & 127;
        int gr = r0b + r;
        float4 v = make_float4(0.f, 0.f, 0.f, 0.f);
        if (gr < n) v = ((const float4*)x)[(gr * 128 + k) >> 2];
        *(float4*)&xs[r][k] = v;
    }
    __syncthreads();

    int tx = threadIdx.x & 15, ty = threadIdx.x >> 4;
    int c0 = tx * 4, r0 = ty * 4;
    float acc[4][4] = {};
    for (int k = 0; k < 128; k++) {
        float4 b = *(const float4*)&ws[k][c0];
        float a0 = xs[r0 + 0][k], a1 = xs[r0 + 1][k], a2 = xs[r0 + 2][k], a3 = xs[r0 + 3][k];
        acc[0][0] += a0 * b.x; acc[0][1] += a0 * b.y; acc[0][2] += a0 * b.z; acc[0][3] += a0 * b.w;
        acc[1][0] += a1 * b.x; acc[1][1] += a1 * b.y; acc[1][2] += a1 * b.z; acc[1][3] += a1 * b.w;
        acc[2][0] += a2 * b.x; acc[2][1] += a2 * b.y; acc[2][2] += a2 * b.z; acc[2][3] += a2 * b.w;
        acc[3][0] += a3 * b.x; acc[3][1] += a3 * b.y; acc[3][2] += a3 * b.z; acc[3][3] += a3 * b.w;
    }
    for (int i = 0; i < 4; i++) {
        int gr = r0b + r0 + i;
        if (gr < n)
            *(float4*)&h1[gr * 64 + c0] = make_float4(acc[i][0], acc[i][1], acc[i][2], acc[i][3]);
    }
}

// ---------------- Aggregation layer 1: block per bucket, LDS accumulator 128x64 ----------------

__global__ __launch_bounds__(256) void agg1_k(const float* __restrict__ h1, const unsigned* __restrict__ recs,
                                              const int* __restrict__ cnt, const float* __restrict__ dis,
                                              float* __restrict__ out, int n) {
    __shared__ __attribute__((aligned(16))) float acc[BK * 64];   // 32 KB
    __shared__ float sdis[BK];
    int b = blockIdx.x;
    int n0 = b * BK;
    // zero acc (8 float4 per thread)
    float4* a4 = (float4*)acc;
    #pragma unroll
    for (int i = 0; i < 8; i++) a4[threadIdx.x + i * 256] = make_float4(0.f, 0.f, 0.f, 0.f);
    if (threadIdx.x < BK) {
        int g = n0 + threadIdx.x;
        sdis[threadIdx.x] = (g < n) ? dis[g] : 0.f;
    }
    __syncthreads();

    int ne = min(cnt[b], CAP);
    const unsigned* base = recs + (size_t)b * CAP;
    int wave = threadIdx.x >> 6, f = threadIdx.x & 63;

    int e = wave;
    for (; e + 4 < ne; e += 8) {
        unsigned r0 = base[e], r1 = base[e + 4];
        int s0 = r0 >> BKSH, d0 = r0 & (BK - 1);
        int s1 = r1 >> BKSH, d1 = r1 & (BK - 1);
        float v0 = h1[s0 * 64 + f], v1 = h1[s1 * 64 + f];
        float w0 = dis[s0] * sdis[d0], w1 = dis[s1] * sdis[d1];
        atomicAdd(&acc[d0 * 64 + f], v0 * w0);
        atomicAdd(&acc[d1 * 64 + f], v1 * w1);
    }
    for (; e < ne; e += 4) {
        unsigned r0 = base[e];
        int s0 = r0 >> BKSH, d0 = r0 & (BK - 1);
        float v0 = h1[s0 * 64 + f];
        atomicAdd(&acc[d0 * 64 + f], v0 * dis[s0] * sdis[d0]);
    }
    __syncthreads();

    // epilogue: += self-loop, store
    for (int i4 = threadIdx.x; i4 < BK * 16; i4 += 256) {
        int r = i4 >> 4, c4 = i4 & 15;
        int g = n0 + r;
        if (g >= n) break;
        float dd = sdis[r] * sdis[r];
        float4 h = ((const float4*)h1)[g * 16 + c4];
        float4 a = ((float4*)acc)[r * 16 + c4];
        a.x += h.x * dd; a.y += h.y * dd; a.z += h.z * dd; a.w += h.w * dd;
        ((float4*)out)[g * 16 + c4] = a;
    }
}

// ---------------- BN stats ----------------

__global__ __launch_bounds__(256) void bnstats_k(const float* __restrict__ agg1, float* __restrict__ stats, int n) {
    int f = threadIdx.x & 63, g = threadIdx.x >> 6;
    float sum = 0.f, sq = 0.f;
    for (int r = blockIdx.x * 4 + g; r < n; r += gridDim.x * 4) {
        float v = agg1[r * 64 + f];
        sum += v; sq += v * v;
    }
    __shared__ float s1[4][64], s2[4][64];
    s1[g][f] = sum; s2[g][f] = sq;
    __syncthreads();
    if (g == 0) {
        sum = s1[0][f] + s1[1][f] + s1[2][f] + s1[3][f];
        sq  = s2[0][f] + s2[1][f] + s2[2][f] + s2[3][f];
        atomicAdd(&stats[f], sum);
        atomicAdd(&stats[64 + f], sq);
    }
}

// BN folded: h = relu(agg1 * s + t);  b1 cancels in centering (shift invariance).
__global__ __launch_bounds__(64) void bnfin_k(const float* __restrict__ stats, const float* __restrict__ gamma,
                                              const float* __restrict__ beta, float* __restrict__ st, float invn) {
    int f = threadIdx.x;
    if (f < 64) {
        float mean = stats[f] * invn;
        float var = stats[64 + f] * invn - mean * mean;
        float s = gamma[f] * rsqrtf(var + BN_EPS);
        st[f] = s;
        st[64 + f] = beta[f] - mean * s;
    }
}

// ---------------- GEMM2: h2 = relu(agg1*s+t) @ W2  (N x 64 @ 64 x 32) ----------------

__global__ __launch_bounds__(256) void gemm2_k(const float* __restrict__ agg1, const float* __restrict__ W2,
                                               const float* __restrict__ st, float* __restrict__ h2, int n) {
    __shared__ __attribute__((aligned(16))) float xs[64][68];
    __shared__ __attribute__((aligned(16))) float ws2[64][32];
    __shared__ float s_s[64], s_t[64];
    if (threadIdx.x < 64) {
        s_s[threadIdx.x] = st[threadIdx.x];
        s_t[threadIdx.x] = st[64 + threadIdx.x];
    }
    for (int i = threadIdx.x; i < 512; i += 256)
        ((float4*)&ws2[0][0])[i] = ((const float4*)W2)[i];
    __syncthreads();

    int r0b = blockIdx.x * 64;
    for (int i = threadIdx.x; i < 1024; i += 256) {
        int lin = i * 4;
        int r = lin >> 6, k = lin & 63;
        int gr = r0b + r;
        float4 v = make_float4(0.f, 0.f, 0.f, 0.f);
        if (gr < n) v = ((const float4*)agg1)[(gr * 64 + k) >> 2];
        v.x = fmaxf(v.x * s_s[k + 0] + s_t[k + 0], 0.f);
        v.y = fmaxf(v.y * s_s[k + 1] + s_t[k + 1], 0.f);
        v.z = fmaxf(v.z * s_s[k + 2] + s_t[k + 2], 0.f);
        v.w = fmaxf(v.w * s_s[k + 3] + s_t[k + 3], 0.f);
        *(float4*)&xs[r][k] = v;
    }
    __syncthreads();

    int c = threadIdx.x & 31, ty = threadIdx.x >> 5;
    float acc[8] = {};
    for (int k = 0; k < 64; k++) {
        float b = ws2[k][c];
        #pragma unroll
        for (int i = 0; i < 8; i++) acc[i] += xs[ty * 8 + i][k] * b;
    }
    for (int i = 0; i < 8; i++) {
        int gr = r0b + ty * 8 + i;
        if (gr < n) h2[gr * 32 + c] = acc[i];
    }
}

// ---------------- Aggregation layer 2: block per bucket, LDS acc 128x32, 2 edges/wave-iter ----------------

__global__ __launch_bounds__(256) void agg2_k(const float* __restrict__ h2, const unsigned* __restrict__ recs,
                                              const int* __restrict__ cnt, const float* __restrict__ dis,
                                              const float* __restrict__ b2, float* __restrict__ out, int n) {
    __shared__ __attribute__((aligned(16))) float acc[BK * 32];   // 16 KB
    __shared__ float sdis[BK];
    int b = blockIdx.x;
    int n0 = b * BK;
    float4* a4 = (float4*)acc;
    #pragma unroll
    for (int i = 0; i < 4; i++) a4[threadIdx.x + i * 256] = make_float4(0.f, 0.f, 0.f, 0.f);
    if (threadIdx.x < BK) {
        int g = n0 + threadIdx.x;
        sdis[threadIdx.x] = (g < n) ? dis[g] : 0.f;
    }
    __syncthreads();

    int ne = min(cnt[b], CAP);
    const unsigned* base = recs + (size_t)b * CAP;
    int wave = threadIdx.x >> 6;
    int lane = threadIdx.x & 63;
    int f = lane & 31, half = lane >> 5;

    int j = wave * 2 + half;   // 0..7
    for (; j + 8 < ne; j += 16) {
        unsigned r0 = base[j], r1 = base[j + 8];
        int s0 = r0 >> BKSH, d0 = r0 & (BK - 1);
        int s1 = r1 >> BKSH, d1 = r1 & (BK - 1);
        float v0 = h2[s0 * 32 + f], v1 = h2[s1 * 32 + f];
        float w0 = dis[s0] * sdis[d0], w1 = dis[s1] * sdis[d1];
        atomicAdd(&acc[d0 * 32 + f], v0 * w0);
        atomicAdd(&acc[d1 * 32 + f], v1 * w1);
    }
    for (; j < ne; j += 8) {
        unsigned r0 = base[j];
        int s0 = r0 >> BKSH, d0 = r0 & (BK - 1);
        float v0 = h2[s0 * 32 + f];
        atomicAdd(&acc[d0 * 32 + f], v0 * dis[s0] * sdis[d0]);
    }
    __syncthreads();

    for (int i4 = threadIdx.x; i4 < BK * 8; i4 += 256) {
        int r = i4 >> 3, c4 = i4 & 7;
        int g = n0 + r;
        if (g >= n) break;
        float dd = sdis[r] * sdis[r];
        float4 h = ((const float4*)h2)[g * 8 + c4];
        float4 a = ((float4*)acc)[r * 8 + c4];
        float4 bb = ((const float4*)b2)[c4 & 7];
        a.x += h.x * dd + bb.x; a.y += h.y * dd + bb.y; a.z += h.z * dd + bb.z; a.w += h.w * dd + bb.w;
        ((float4*)out)[g * 8 + c4] = a;
    }
}

// ---------------- launch ----------------

extern "C" void kernel_launch(void* const* d_in, const int* in_sizes, int n_in,
                              void* d_out, int out_size, void* d_ws, size_t ws_size,
                              hipStream_t stream) {
    const float* x      = (const float*)d_in[0];
    const int*   ei     = (const int*)d_in[1];
    const float* W1     = (const float*)d_in[2];
    // d_in[3] = b1 (cancels inside BN)
    const float* gamma1 = (const float*)d_in[4];
    const float* beta1  = (const float*)d_in[5];
    const float* W2     = (const float*)d_in[6];
    const float* b2     = (const float*)d_in[7];
    float* out = (float*)d_out;

    int N = in_sizes[0] / DIN;
    int E = in_sizes[1] / 2;
    const int* src = ei;
    const int* dst = ei + E;
    int NB = (N + BK - 1) / BK;   // buckets

    size_t off = 0;  // 4B units
    auto alloc = [&](size_t elems) -> void* {
        void* p = (char*)d_ws + off * 4;
        off += (elems + 127) & ~size_t(127);
        return p;
    };
    int*      cnt   = (int*)alloc(NB);
    unsigned* recs  = (unsigned*)alloc((size_t)NB * CAP);
    float*    dis   = (float*)alloc(N);
    float*    stats = (float*)alloc(128);
    float*    st    = (float*)alloc(128);
    float*    h1    = (float*)alloc((size_t)N * DH);
    float*    agg1  = (float*)alloc((size_t)N * DH);
    float*    h2    = h1;  // h1 dead after agg1_k; N*32 <= N*64

    hipMemsetAsync(cnt, 0, (size_t)NB * sizeof(int), stream);
    hipMemsetAsync(stats, 0, 128 * sizeof(float), stream);

    int gE = (E + 255) / 256;
    binscatter_k<<<gE, 256, 0, stream>>>(src, dst, cnt, recs, E);
    deg_k<<<NB, 256, 0, stream>>>(recs, cnt, dis, N);

    gemm1_k<<<(N + 63) / 64, 256, 0, stream>>>(x, W1, h1, N);
    agg1_k<<<NB, 256, 0, stream>>>(h1, recs, cnt, dis, agg1, N);

    bnstats_k<<<400, 256, 0, stream>>>(agg1, stats, N);
    bnfin_k<<<1, 64, 0, stream>>>(stats, gamma1, beta1, st, 1.0f / (float)N);

    gemm2_k<<<(N + 63) / 64, 256, 0, stream>>>(agg1, W2, st, h2, N);
    agg2_k<<<NB, 256, 0, stream>>>(h2, recs, cnt, dis, b2, out, N);
}

// Round 3
// 705.102 us; speedup vs baseline: 2.2636x; 2.2636x over previous
//
#include <hip/hip_runtime.h>

#define DIN 128
#define DH 64
#define DOUT 32
#define BN_EPS 1e-5f

#define BK 128          // nodes per bucket
#define BKSH 7          // log2(BK)
#define CAP 2560        // max edges per bucket (mean ~2046, +11 sigma)

// ---------------- bucket binning: recs[b*CAP + k] = (src<<7) | dst_local ----------------

__global__ __launch_bounds__(256) void binscatter_k(const int* __restrict__ src, const int* __restrict__ dst,
                                                    int* __restrict__ cnt, unsigned* __restrict__ recs, int E) {
    int i = blockIdx.x * 256 + threadIdx.x;
    if (i < E) {
        int s = src[i], d = dst[i];
        int b = d >> BKSH, dl = d & (BK - 1);
        int r = atomicAdd(&cnt[b], 1);
        if (r < CAP) recs[b * CAP + r] = ((unsigned)s << BKSH) | (unsigned)dl;
    }
}

// ---------------- bucket -> node-sorted CSR (LDS histogram + scan + scatter) ----------------
// col[] gets src ids grouped by dst; rpde[g] = {start, deg}; dis[g] = rsqrt(deg+1)

__global__ __launch_bounds__(256) void csr_k(const unsigned* __restrict__ recs, const int* __restrict__ cnt,
                                             float* __restrict__ dis, int2* __restrict__ rpde,
                                             int* __restrict__ col, int n) {
    __shared__ int deg[BK], bas[BK], cur[BK], sc[BK];
    int b = blockIdx.x, tid = threadIdx.x;
    if (tid < BK) { deg[tid] = 0; cur[tid] = 0; }
    __syncthreads();
    int ne = min(cnt[b], CAP);
    const unsigned* rb = recs + (size_t)b * CAP;
    for (int e = tid; e < ne; e += 256) atomicAdd(&deg[rb[e] & (BK - 1)], 1);
    __syncthreads();
    if (tid < BK) sc[tid] = deg[tid];
    __syncthreads();
    for (int off = 1; off < BK; off <<= 1) {
        int t = (tid >= off && tid < BK) ? sc[tid - off] : 0;
        __syncthreads();
        if (tid < BK) sc[tid] += t;
        __syncthreads();
    }
    if (tid < BK) {
        bas[tid] = sc[tid] - deg[tid];
        int g = b * BK + tid;
        if (g < n) {
            dis[g] = rsqrtf((float)(deg[tid] + 1));   // +1 self-loop
            rpde[g] = make_int2(b * CAP + bas[tid], deg[tid]);
        }
    }
    __syncthreads();
    for (int e = tid; e < ne; e += 256) {
        unsigned r = rb[e];
        int dl = r & (BK - 1);
        int k = atomicAdd(&cur[dl], 1);
        col[b * CAP + bas[dl] + k] = (int)(r >> BKSH);
    }
}

// ---------------- GEMM1: h1s = (x @ W1) * dis[row]  (N x 128 @ 128 x 64) ----------------

__global__ __launch_bounds__(256) void gemm1_k(const float* __restrict__ x, const float* __restrict__ W1,
                                               const float* __restrict__ dis, float* __restrict__ h1s, int n) {
    __shared__ __attribute__((aligned(16))) float xs[64][132];
    __shared__ __attribute__((aligned(16))) float ws[128][64];
    int r0b = blockIdx.x * 64;

    const float4* w4 = (const float4*)W1;
    float4* ws4 = (float4*)&ws[0][0];
    for (int i = threadIdx.x; i < 2048; i += 256) ws4[i] = w4[i];
    for (int i = threadIdx.x; i < 2048; i += 256) {
        int lin = i * 4;
        int r = lin >> 7, k = lin & 127;
        int gr = r0b + r;
        float4 v = make_float4(0.f, 0.f, 0.f, 0.f);
        if (gr < n) v = ((const float4*)x)[(gr * 128 + k) >> 2];
        *(float4*)&xs[r][k] = v;
    }
    __syncthreads();

    int tx = threadIdx.x & 15, ty = threadIdx.x >> 4;
    int c0 = tx * 4, r0 = ty * 4;
    float acc[4][4] = {};
    for (int k = 0; k < 128; k++) {
        float4 b = *(const float4*)&ws[k][c0];
        float a0 = xs[r0 + 0][k], a1 = xs[r0 + 1][k], a2 = xs[r0 + 2][k], a3 = xs[r0 + 3][k];
        acc[0][0] += a0 * b.x; acc[0][1] += a0 * b.y; acc[0][2] += a0 * b.z; acc[0][3] += a0 * b.w;
        acc[1][0] += a1 * b.x; acc[1][1] += a1 * b.y; acc[1][2] += a1 * b.z; acc[1][3] += a1 * b.w;
        acc[2][0] += a2 * b.x; acc[2][1] += a2 * b.y; acc[2][2] += a2 * b.z; acc[2][3] += a2 * b.w;
        acc[3][0] += a3 * b.x; acc[3][1] += a3 * b.y; acc[3][2] += a3 * b.z; acc[3][3] += a3 * b.w;
    }
    for (int i = 0; i < 4; i++) {
        int gr = r0b + r0 + i;
        if (gr < n) {
            float dd = dis[gr];
            *(float4*)&h1s[gr * 64 + c0] =
                make_float4(acc[i][0] * dd, acc[i][1] * dd, acc[i][2] * dd, acc[i][3] * dd);
        }
    }
}

// ---------------- Aggregation layer 1: wave per node, 64 lanes = 64 feats, pure gather-sum ----------------

__global__ __launch_bounds__(256) void agg1_k(const float* __restrict__ h1s, const int2* __restrict__ rpde,
                                              const int* __restrict__ col, float* __restrict__ out, int n) {
    int node = (blockIdx.x * 256 + threadIdx.x) >> 6;
    int f = threadIdx.x & 63;
    if (node >= n) return;
    int2 rd = rpde[node];
    int e = rd.x, ee = rd.x + rd.y;
    float a0 = 0.f, a1 = 0.f, a2 = 0.f, a3 = 0.f;
    for (; e + 3 < ee; e += 4) {
        int s0 = col[e], s1 = col[e + 1], s2 = col[e + 2], s3 = col[e + 3];
        a0 += h1s[s0 * 64 + f];
        a1 += h1s[s1 * 64 + f];
        a2 += h1s[s2 * 64 + f];
        a3 += h1s[s3 * 64 + f];
    }
    for (; e < ee; e++) a0 += h1s[col[e] * 64 + f];
    float dn = rsqrtf((float)(rd.y + 1));
    out[node * 64 + f] = (a0 + a1 + a2 + a3 + h1s[node * 64 + f]) * dn;
}

// ---------------- BN stats ----------------

__global__ __launch_bounds__(256) void bnstats_k(const float* __restrict__ agg1, float* __restrict__ stats, int n) {
    int f = threadIdx.x & 63, g = threadIdx.x >> 6;
    float sum = 0.f, sq = 0.f;
    for (int r = blockIdx.x * 4 + g; r < n; r += gridDim.x * 4) {
        float v = agg1[r * 64 + f];
        sum += v; sq += v * v;
    }
    __shared__ float s1[4][64], s2[4][64];
    s1[g][f] = sum; s2[g][f] = sq;
    __syncthreads();
    if (g == 0) {
        sum = s1[0][f] + s1[1][f] + s1[2][f] + s1[3][f];
        sq  = s2[0][f] + s2[1][f] + s2[2][f] + s2[3][f];
        atomicAdd(&stats[f], sum);
        atomicAdd(&stats[64 + f], sq);
    }
}

// BN folded: h = relu(agg1 * s + t);  b1 cancels in centering (shift invariance).
__global__ __launch_bounds__(64) void bnfin_k(const float* __restrict__ stats, const float* __restrict__ gamma,
                                              const float* __restrict__ beta, float* __restrict__ st, float invn) {
    int f = threadIdx.x;
    if (f < 64) {
        float mean = stats[f] * invn;
        float var = stats[64 + f] * invn - mean * mean;
        float s = gamma[f] * rsqrtf(var + BN_EPS);
        st[f] = s;
        st[64 + f] = beta[f] - mean * s;
    }
}

// ---------------- GEMM2: h2s = (relu(agg1*s+t) @ W2) * dis[row]  (N x 64 @ 64 x 32) ----------------

__global__ __launch_bounds__(256) void gemm2_k(const float* __restrict__ agg1, const float* __restrict__ W2,
                                               const float* __restrict__ st, const float* __restrict__ dis,
                                               float* __restrict__ h2s, int n) {
    __shared__ __attribute__((aligned(16))) float xs[64][68];
    __shared__ __attribute__((aligned(16))) float ws2[64][32];
    __shared__ float s_s[64], s_t[64];
    if (threadIdx.x < 64) {
        s_s[threadIdx.x] = st[threadIdx.x];
        s_t[threadIdx.x] = st[64 + threadIdx.x];
    }
    for (int i = threadIdx.x; i < 512; i += 256)
        ((float4*)&ws2[0][0])[i] = ((const float4*)W2)[i];
    __syncthreads();

    int r0b = blockIdx.x * 64;
    for (int i = threadIdx.x; i < 1024; i += 256) {
        int lin = i * 4;
        int r = lin >> 6, k = lin & 63;
        int gr = r0b + r;
        float4 v = make_float4(0.f, 0.f, 0.f, 0.f);
        if (gr < n) v = ((const float4*)agg1)[(gr * 64 + k) >> 2];
        v.x = fmaxf(v.x * s_s[k + 0] + s_t[k + 0], 0.f);
        v.y = fmaxf(v.y * s_s[k + 1] + s_t[k + 1], 0.f);
        v.z = fmaxf(v.z * s_s[k + 2] + s_t[k + 2], 0.f);
        v.w = fmaxf(v.w * s_s[k + 3] + s_t[k + 3], 0.f);
        *(float4*)&xs[r][k] = v;
    }
    __syncthreads();

    int c = threadIdx.x & 31, ty = threadIdx.x >> 5;
    float acc[8] = {};
    for (int k = 0; k < 64; k++) {
        float b = ws2[k][c];
        #pragma unroll
        for (int i = 0; i < 8; i++) acc[i] += xs[ty * 8 + i][k] * b;
    }
    for (int i = 0; i < 8; i++) {
        int gr = r0b + ty * 8 + i;
        if (gr < n) h2s[gr * 32 + c] = acc[i] * dis[gr];
    }
}

// ---------------- Aggregation layer 2: wave per node, 2 half-waves x 32 feats ----------------

__global__ __launch_bounds__(256) void agg2_k(const float* __restrict__ h2s, const int2* __restrict__ rpde,
                                              const int* __restrict__ col, const float* __restrict__ b2,
                                              float* __restrict__ out, int n) {
    int node = (blockIdx.x * 256 + threadIdx.x) >> 6;
    int lane = threadIdx.x & 63;
    if (node >= n) return;
    int f = lane & 31, half = lane >> 5;
    int2 rd = rpde[node];
    int e = rd.x + half, ee = rd.x + rd.y;
    float a0 = 0.f, a1 = 0.f;
    for (; e + 2 < ee; e += 4) {
        int s0 = col[e], s1 = col[e + 2];
        a0 += h2s[s0 * 32 + f];
        a1 += h2s[s1 * 32 + f];
    }
    for (; e < ee; e += 2) a0 += h2s[col[e] * 32 + f];
    float acc = a0 + a1;
    acc += __shfl_down(acc, 32, 64);
    if (half == 0) {
        float dn = rsqrtf((float)(rd.y + 1));
        out[node * 32 + f] = (acc + h2s[node * 32 + f]) * dn + b2[f];
    }
}

// ---------------- launch ----------------

extern "C" void kernel_launch(void* const* d_in, const int* in_sizes, int n_in,
                              void* d_out, int out_size, void* d_ws, size_t ws_size,
                              hipStream_t stream) {
    const float* x      = (const float*)d_in[0];
    const int*   ei     = (const int*)d_in[1];
    const float* W1     = (const float*)d_in[2];
    // d_in[3] = b1 (cancels inside BN)
    const float* gamma1 = (const float*)d_in[4];
    const float* beta1  = (const float*)d_in[5];
    const float* W2     = (const float*)d_in[6];
    const float* b2     = (const float*)d_in[7];
    float* out = (float*)d_out;

    int N = in_sizes[0] / DIN;
    int E = in_sizes[1] / 2;
    const int* src = ei;
    const int* dst = ei + E;
    int NB = (N + BK - 1) / BK;   // buckets

    size_t off = 0;  // 4B units
    auto alloc = [&](size_t elems) -> void* {
        void* p = (char*)d_ws + off * 4;
        off += (elems + 127) & ~size_t(127);
        return p;
    };
    int*      cnt   = (int*)alloc(NB);
    unsigned* recs  = (unsigned*)alloc((size_t)NB * CAP);
    int*      col   = (int*)alloc((size_t)NB * CAP);
    float*    dis   = (float*)alloc(N);
    int2*     rpde  = (int2*)alloc((size_t)N * 2);
    float*    stats = (float*)alloc(128);
    float*    st    = (float*)alloc(128);
    float*    h1s   = (float*)alloc((size_t)N * DH);
    float*    agg1  = (float*)alloc((size_t)N * DH);
    float*    h2s   = h1s;  // h1s dead after agg1_k; N*32 <= N*64

    hipMemsetAsync(cnt, 0, (size_t)NB * sizeof(int), stream);
    hipMemsetAsync(stats, 0, 128 * sizeof(float), stream);

    int gE = (E + 255) / 256;
    binscatter_k<<<gE, 256, 0, stream>>>(src, dst, cnt, recs, E);
    csr_k<<<NB, 256, 0, stream>>>(recs, cnt, dis, rpde, col, N);

    gemm1_k<<<(N + 63) / 64, 256, 0, stream>>>(x, W1, dis, h1s, N);
    agg1_k<<<(N + 3) / 4, 256, 0, stream>>>(h1s, rpde, col, agg1, N);

    bnstats_k<<<400, 256, 0, stream>>>(agg1, stats, N);
    bnfin_k<<<1, 64, 0, stream>>>(stats, gamma1, beta1, st, 1.0f / (float)N);

    gemm2_k<<<(N + 63) / 64, 256, 0, stream>>>(agg1, W2, st, dis, h2s, N);
    agg2_k<<<(N + 3) / 4, 256, 0, stream>>>(h2s, rpde, col, b2, out, N);
}

// Round 4
// 409.644 us; speedup vs baseline: 3.8962x; 1.7213x over previous
//
#include <hip/hip_runtime.h>

#define DIN 128
#define DH 64
#define DOUT 32
#define BN_EPS 1e-5f

#define BK 128          // nodes per bucket
#define BKSH 7          // log2(BK)
#define CAP 2560        // max edges per bucket in node-sorted col[] (mean ~2046, +11 sigma)
#define NSUB 32         // cursors per bucket: 8 XCD shards x 4 wave sub-cursors
#define SUBCAP 128      // slots per sub-list (mean ~64, huge headroom)

// ---------------- bucket binning, XCD-sharded cursors ----------------
// recs[((b*NSUB + cursor) * SUBCAP) + slot] = (src << 7) | dst_local
// cursor = (blockIdx&7)*4 + (wave&3): same cursor+region touched by ~one XCD ->
// no cross-XCD line ping-pong on the atomic, no partial-line writeback storm.

__global__ __launch_bounds__(256) void binscatter_k(const int* __restrict__ src, const int* __restrict__ dst,
                                                    int* __restrict__ cnt, unsigned* __restrict__ recs, int E) {
    int i = blockIdx.x * 256 + threadIdx.x;
    int cursor = ((blockIdx.x & 7) << 2) | ((threadIdx.x >> 6) & 3);
    if (i < E) {
        int s = src[i], d = dst[i];
        int b = d >> BKSH, dl = d & (BK - 1);
        int c = b * NSUB + cursor;
        int r = atomicAdd(&cnt[c], 1);
        if (r < SUBCAP) recs[(size_t)c * SUBCAP + r] = ((unsigned)s << BKSH) | (unsigned)dl;
    }
}

// ---------------- bucket (32 sub-lists) -> node-sorted CSR ----------------
// col[] gets src ids grouped by dst; rpde[g] = {start, deg}; dis[g] = rsqrt(deg+1)

__global__ __launch_bounds__(256) void csr_k(const unsigned* __restrict__ recs, const int* __restrict__ cnt,
                                             float* __restrict__ dis, int2* __restrict__ rpde,
                                             int* __restrict__ col, int n) {
    __shared__ int deg[BK], bas[BK], cur[BK], sc[BK];
    __shared__ int scnt[NSUB];
    int b = blockIdx.x, tid = threadIdx.x;
    if (tid < BK) { deg[tid] = 0; cur[tid] = 0; }
    if (tid < NSUB) scnt[tid] = min(cnt[b * NSUB + tid], SUBCAP);
    __syncthreads();
    const unsigned* rb = recs + (size_t)b * NSUB * SUBCAP;
    // histogram over all 32 sub-lists (flattened 4096 slots)
    for (int s = tid; s < NSUB * SUBCAP; s += 256) {
        if ((s & (SUBCAP - 1)) < scnt[s >> 7])
            atomicAdd(&deg[rb[s] & (BK - 1)], 1);
    }
    __syncthreads();
    if (tid < BK) sc[tid] = deg[tid];
    __syncthreads();
    for (int off = 1; off < BK; off <<= 1) {
        int t = (tid >= off && tid < BK) ? sc[tid - off] : 0;
        __syncthreads();
        if (tid < BK) sc[tid] += t;
        __syncthreads();
    }
    if (tid < BK) {
        bas[tid] = sc[tid] - deg[tid];
        int g = b * BK + tid;
        if (g < n) {
            dis[g] = rsqrtf((float)(deg[tid] + 1));   // +1 self-loop
            rpde[g] = make_int2(b * CAP + bas[tid], deg[tid]);
        }
    }
    __syncthreads();
    for (int s = tid; s < NSUB * SUBCAP; s += 256) {
        if ((s & (SUBCAP - 1)) < scnt[s >> 7]) {
            unsigned r = rb[s];
            int dl = r & (BK - 1);
            int k = atomicAdd(&cur[dl], 1);
            col[b * CAP + bas[dl] + k] = (int)(r >> BKSH);
        }
    }
}

// ---------------- GEMM1: h1s = (x @ W1) * dis[row]  (N x 128 @ 128 x 64) ----------------

__global__ __launch_bounds__(256) void gemm1_k(const float* __restrict__ x, const float* __restrict__ W1,
                                               const float* __restrict__ dis, float* __restrict__ h1s, int n) {
    __shared__ __attribute__((aligned(16))) float xs[64][132];
    __shared__ __attribute__((aligned(16))) float ws[128][64];
    int r0b = blockIdx.x * 64;

    const float4* w4 = (const float4*)W1;
    float4* ws4 = (float4*)&ws[0][0];
    for (int i = threadIdx.x; i < 2048; i += 256) ws4[i] = w4[i];
    for (int i = threadIdx.x; i < 2048; i += 256) {
        int lin = i * 4;
        int r = lin >> 7, k = lin & 127;
        int gr = r0b + r;
        float4 v = make_float4(0.f, 0.f, 0.f, 0.f);
        if (gr < n) v = ((const float4*)x)[(gr * 128 + k) >> 2];
        *(float4*)&xs[r][k] = v;
    }
    __syncthreads();

    int tx = threadIdx.x & 15, ty = threadIdx.x >> 4;
    int c0 = tx * 4, r0 = ty * 4;
    float acc[4][4] = {};
    for (int k = 0; k < 128; k++) {
        float4 b = *(const float4*)&ws[k][c0];
        float a0 = xs[r0 + 0][k], a1 = xs[r0 + 1][k], a2 = xs[r0 + 2][k], a3 = xs[r0 + 3][k];
        acc[0][0] += a0 * b.x; acc[0][1] += a0 * b.y; acc[0][2] += a0 * b.z; acc[0][3] += a0 * b.w;
        acc[1][0] += a1 * b.x; acc[1][1] += a1 * b.y; acc[1][2] += a1 * b.z; acc[1][3] += a1 * b.w;
        acc[2][0] += a2 * b.x; acc[2][1] += a2 * b.y; acc[2][2] += a2 * b.z; acc[2][3] += a2 * b.w;
        acc[3][0] += a3 * b.x; acc[3][1] += a3 * b.y; acc[3][2] += a3 * b.z; acc[3][3] += a3 * b.w;
    }
    for (int i = 0; i < 4; i++) {
        int gr = r0b + r0 + i;
        if (gr < n) {
            float dd = dis[gr];
            *(float4*)&h1s[gr * 64 + c0] =
                make_float4(acc[i][0] * dd, acc[i][1] * dd, acc[i][2] * dd, acc[i][3] * dd);
        }
    }
}

// ---------------- Aggregation layer 1: wave per node, 64 lanes = 64 feats, pure gather-sum ----------------

__global__ __launch_bounds__(256) void agg1_k(const float* __restrict__ h1s, const int2* __restrict__ rpde,
                                              const int* __restrict__ col, float* __restrict__ out, int n) {
    int node = (blockIdx.x * 256 + threadIdx.x) >> 6;
    int f = threadIdx.x & 63;
    if (node >= n) return;
    int2 rd = rpde[node];
    int e = rd.x, ee = rd.x + rd.y;
    float a0 = 0.f, a1 = 0.f, a2 = 0.f, a3 = 0.f;
    for (; e + 3 < ee; e += 4) {
        int s0 = col[e], s1 = col[e + 1], s2 = col[e + 2], s3 = col[e + 3];
        a0 += h1s[s0 * 64 + f];
        a1 += h1s[s1 * 64 + f];
        a2 += h1s[s2 * 64 + f];
        a3 += h1s[s3 * 64 + f];
    }
    for (; e < ee; e++) a0 += h1s[col[e] * 64 + f];
    float dn = rsqrtf((float)(rd.y + 1));
    out[node * 64 + f] = (a0 + a1 + a2 + a3 + h1s[node * 64 + f]) * dn;
}

// ---------------- BN stats ----------------

__global__ __launch_bounds__(256) void bnstats_k(const float* __restrict__ agg1, float* __restrict__ stats, int n) {
    int f = threadIdx.x & 63, g = threadIdx.x >> 6;
    float sum = 0.f, sq = 0.f;
    for (int r = blockIdx.x * 4 + g; r < n; r += gridDim.x * 4) {
        float v = agg1[r * 64 + f];
        sum += v; sq += v * v;
    }
    __shared__ float s1[4][64], s2[4][64];
    s1[g][f] = sum; s2[g][f] = sq;
    __syncthreads();
    if (g == 0) {
        sum = s1[0][f] + s1[1][f] + s1[2][f] + s1[3][f];
        sq  = s2[0][f] + s2[1][f] + s2[2][f] + s2[3][f];
        atomicAdd(&stats[f], sum);
        atomicAdd(&stats[64 + f], sq);
    }
}

// BN folded: h = relu(agg1 * s + t);  b1 cancels in centering (shift invariance).
__global__ __launch_bounds__(64) void bnfin_k(const float* __restrict__ stats, const float* __restrict__ gamma,
                                              const float* __restrict__ beta, float* __restrict__ st, float invn) {
    int f = threadIdx.x;
    if (f < 64) {
        float mean = stats[f] * invn;
        float var = stats[64 + f] * invn - mean * mean;
        float s = gamma[f] * rsqrtf(var + BN_EPS);
        st[f] = s;
        st[64 + f] = beta[f] - mean * s;
    }
}

// ---------------- GEMM2: h2s = (relu(agg1*s+t) @ W2) * dis[row]  (N x 64 @ 64 x 32) ----------------

__global__ __launch_bounds__(256) void gemm2_k(const float* __restrict__ agg1, const float* __restrict__ W2,
                                               const float* __restrict__ st, const float* __restrict__ dis,
                                               float* __restrict__ h2s, int n) {
    __shared__ __attribute__((aligned(16))) float xs[64][68];
    __shared__ __attribute__((aligned(16))) float ws2[64][32];
    __shared__ float s_s[64], s_t[64];
    if (threadIdx.x < 64) {
        s_s[threadIdx.x] = st[threadIdx.x];
        s_t[threadIdx.x] = st[64 + threadIdx.x];
    }
    for (int i = threadIdx.x; i < 512; i += 256)
        ((float4*)&ws2[0][0])[i] = ((const float4*)W2)[i];
    __syncthreads();

    int r0b = blockIdx.x * 64;
    for (int i = threadIdx.x; i < 1024; i += 256) {
        int lin = i * 4;
        int r = lin >> 6, k = lin & 63;
        int gr = r0b + r;
        float4 v = make_float4(0.f, 0.f, 0.f, 0.f);
        if (gr < n) v = ((const float4*)agg1)[(gr * 64 + k) >> 2];
        v.x = fmaxf(v.x * s_s[k + 0] + s_t[k + 0], 0.f);
        v.y = fmaxf(v.y * s_s[k + 1] + s_t[k + 1], 0.f);
        v.z = fmaxf(v.z * s_s[k + 2] + s_t[k + 2], 0.f);
        v.w = fmaxf(v.w * s_s[k + 3] + s_t[k + 3], 0.f);
        *(float4*)&xs[r][k] = v;
    }
    __syncthreads();

    int c = threadIdx.x & 31, ty = threadIdx.x >> 5;
    float acc[8] = {};
    for (int k = 0; k < 64; k++) {
        float b = ws2[k][c];
        #pragma unroll
        for (int i = 0; i < 8; i++) acc[i] += xs[ty * 8 + i][k] * b;
    }
    for (int i = 0; i < 8; i++) {
        int gr = r0b + ty * 8 + i;
        if (gr < n) h2s[gr * 32 + c] = acc[i] * dis[gr];
    }
}

// ---------------- Aggregation layer 2: wave per node, 2 half-waves x 32 feats ----------------

__global__ __launch_bounds__(256) void agg2_k(const float* __restrict__ h2s, const int2* __restrict__ rpde,
                                              const int* __restrict__ col, const float* __restrict__ b2,
                                              float* __restrict__ out, int n) {
    int node = (blockIdx.x * 256 + threadIdx.x) >> 6;
    int lane = threadIdx.x & 63;
    if (node >= n) return;
    int f = lane & 31, half = lane >> 5;
    int2 rd = rpde[node];
    int e = rd.x + half, ee = rd.x + rd.y;
    float a0 = 0.f, a1 = 0.f;
    for (; e + 2 < ee; e += 4) {
        int s0 = col[e], s1 = col[e + 2];
        a0 += h2s[s0 * 32 + f];
        a1 += h2s[s1 * 32 + f];
    }
    for (; e < ee; e += 2) a0 += h2s[col[e] * 32 + f];
    float acc = a0 + a1;
    acc += __shfl_down(acc, 32, 64);
    if (half == 0) {
        float dn = rsqrtf((float)(rd.y + 1));
        out[node * 32 + f] = (acc + h2s[node * 32 + f]) * dn + b2[f];
    }
}

// ---------------- launch ----------------

extern "C" void kernel_launch(void* const* d_in, const int* in_sizes, int n_in,
                              void* d_out, int out_size, void* d_ws, size_t ws_size,
                              hipStream_t stream) {
    const float* x      = (const float*)d_in[0];
    const int*   ei     = (const int*)d_in[1];
    const float* W1     = (const float*)d_in[2];
    // d_in[3] = b1 (cancels inside BN)
    const float* gamma1 = (const float*)d_in[4];
    const float* beta1  = (const float*)d_in[5];
    const float* W2     = (const float*)d_in[6];
    const float* b2     = (const float*)d_in[7];
    float* out = (float*)d_out;

    int N = in_sizes[0] / DIN;
    int E = in_sizes[1] / 2;
    const int* src = ei;
    const int* dst = ei + E;
    int NB = (N + BK - 1) / BK;   // buckets

    size_t off = 0;  // 4B units
    auto alloc = [&](size_t elems) -> void* {
        void* p = (char*)d_ws + off * 4;
        off += (elems + 127) & ~size_t(127);
        return p;
    };
    int*      cnt   = (int*)alloc((size_t)NB * NSUB);
    unsigned* recs  = (unsigned*)alloc((size_t)NB * NSUB * SUBCAP);
    int*      col   = (int*)alloc((size_t)NB * CAP);
    float*    dis   = (float*)alloc(N);
    int2*     rpde  = (int2*)alloc((size_t)N * 2);
    float*    stats = (float*)alloc(128);
    float*    st    = (float*)alloc(128);
    float*    h1s   = (float*)alloc((size_t)N * DH);
    float*    agg1  = (float*)alloc((size_t)N * DH);
    float*    h2s   = h1s;  // h1s dead after agg1_k; N*32 <= N*64

    hipMemsetAsync(cnt, 0, (size_t)NB * NSUB * sizeof(int), stream);
    hipMemsetAsync(stats, 0, 128 * sizeof(float), stream);

    int gE = (E + 255) / 256;
    binscatter_k<<<gE, 256, 0, stream>>>(src, dst, cnt, recs, E);
    csr_k<<<NB, 256, 0, stream>>>(recs, cnt, dis, rpde, col, N);

    gemm1_k<<<(N + 63) / 64, 256, 0, stream>>>(x, W1, dis, h1s, N);
    agg1_k<<<(N + 3) / 4, 256, 0, stream>>>(h1s, rpde, col, agg1, N);

    bnstats_k<<<400, 256, 0, stream>>>(agg1, stats, N);
    bnfin_k<<<1, 64, 0, stream>>>(stats, gamma1, beta1, st, 1.0f / (float)N);

    gemm2_k<<<(N + 63) / 64, 256, 0, stream>>>(agg1, W2, st, dis, h2s, N);
    agg2_k<<<(N + 3) / 4, 256, 0, stream>>>(h2s, rpde, col, b2, out, N);
}